// Round 1
// baseline (387.868 us; speedup 1.0000x reference)
//
#include <hip/hip_runtime.h>
#include <hip/hip_bf16.h>

#define E_EDGES   1000000
#define N_TILES   15625     // E / 64
#define IN_DIM_K  128
#define HID_N     256
#define BN_EPS_F  1e-5f
#define MAIN_GRID 512

typedef __attribute__((ext_vector_type(4))) float f32x4;
typedef __attribute__((ext_vector_type(8))) short bf16x8;

__device__ __forceinline__ unsigned short f2bf(float f) {
    __hip_bfloat16 h = __float2bfloat16(f);
    return *reinterpret_cast<unsigned short*>(&h);
}
__device__ __forceinline__ unsigned pack2(float lo, float hi) {
    return (unsigned)f2bf(lo) | ((unsigned)f2bf(hi) << 16);
}

union FragU { uint4 u; bf16x8 v; unsigned w[4]; };

__global__ void zero_stats_kernel(float* g) {
    g[threadIdx.x] = 0.0f;   // 512 threads
}

__global__ void finalize_stats_kernel(const float* __restrict__ gstat,
                                      const float* __restrict__ gamma,
                                      const float* __restrict__ beta,
                                      float* __restrict__ nAB) {
    int c = threadIdx.x;     // 256 threads
    float inv_e = 1.0f / (float)E_EDGES;
    float mean = gstat[c] * inv_e;
    float var  = fmaxf(gstat[256 + c] * inv_e - mean * mean, 0.0f);
    float a = gamma[c] * rsqrtf(var + BN_EPS_F);
    nAB[c] = a;
    nAB[256 + c] = beta[c] - mean * a;
}

// Block: 512 threads = 8 waves, wave grid 2(m) x 4(n).
// Tile: 64 edges x 256 channels, K = 128 (4 MFMA k-steps of 32).
// W1 B-fragments held in registers across the whole grid-stride loop.
template <bool STATS>
__global__ __launch_bounds__(512, 2)
void hadamard_mlp_kernel(const float* __restrict__ nodes,
                         const int* __restrict__ eidx,
                         const float* __restrict__ W1,
                         const float* __restrict__ W2,
                         const float* __restrict__ b2p,
                         float* __restrict__ gstat,
                         const float* __restrict__ nAB,
                         float* __restrict__ y)
{
    __shared__ unsigned sh_d[64 * 68];   // 64 rows x 136 bf16 (stride-padded)
    __shared__ float s_red[512];

    const int tid  = threadIdx.x;
    const int lane = tid & 63;
    const int w    = tid >> 6;
    const int wm   = w >> 2;
    const int wn   = w & 3;
    const int l15  = lane & 15;
    const int l4   = lane >> 4;

    // ---- B fragments from W1 (f32 [128][256] row-major, strided read) ----
    bf16x8 bfrag[4][4];
    #pragma unroll
    for (int nt = 0; nt < 4; ++nt) {
        const int c = wn * 64 + nt * 16 + l15;
        #pragma unroll
        for (int kk = 0; kk < 4; ++kk) {
            const int kb = kk * 32 + 8 * l4;
            FragU t;
            #pragma unroll
            for (int j = 0; j < 4; ++j) {
                float w0 = W1[(kb + 2 * j    ) * HID_N + c];
                float w1 = W1[(kb + 2 * j + 1) * HID_N + c];
                t.w[j] = pack2(w0, w1);
            }
            bfrag[nt][kk] = t.v;
        }
    }

    float a_n[4], b_n[4], w2_n[4];
    if (!STATS) {
        #pragma unroll
        for (int nt = 0; nt < 4; ++nt) {
            const int c = wn * 64 + nt * 16 + l15;
            a_n[nt]  = nAB[c];
            b_n[nt]  = nAB[256 + c];
            w2_n[nt] = W2[c];
        }
    }
    const float b2v = b2p[0];

    float s1[4] = {0.f, 0.f, 0.f, 0.f};
    float s2[4] = {0.f, 0.f, 0.f, 0.f};

    const int ge   = tid >> 3;   // local edge 0..63
    const int part = tid & 7;    // 16-float chunk of the 128-dim row

    for (int tile = blockIdx.x; tile < N_TILES; tile += gridDim.x) {
        __syncthreads();
        // ---- stage d = out[src] * out[dst] into LDS as bf16 ----
        {
            const int e = tile * 64 + ge;
            const long long s  = eidx[e];
            const long long d0 = eidx[E_EDGES + e];
            const float4* ps = reinterpret_cast<const float4*>(nodes + s  * IN_DIM_K) + part * 4;
            const float4* pd = reinterpret_cast<const float4*>(nodes + d0 * IN_DIM_K) + part * 4;
            unsigned buf[8];
            #pragma unroll
            for (int j = 0; j < 4; ++j) {
                float4 a = ps[j];
                float4 b = pd[j];
                buf[2 * j]     = pack2(a.x * b.x, a.y * b.y);
                buf[2 * j + 1] = pack2(a.z * b.z, a.w * b.w);
            }
            unsigned* dst = sh_d + ge * 68 + part * 8;
            *reinterpret_cast<uint4*>(dst)     = *reinterpret_cast<const uint4*>(buf);
            *reinterpret_cast<uint4*>(dst + 4) = *reinterpret_cast<const uint4*>(buf + 4);
        }
        __syncthreads();

        // ---- MFMA: hraw tile (this wave: 32 edges x 64 channels) ----
        f32x4 acc[2][4] = {};
        #pragma unroll
        for (int kk = 0; kk < 4; ++kk) {
            bf16x8 af[2];
            #pragma unroll
            for (int mt = 0; mt < 2; ++mt) {
                const int row = wm * 32 + mt * 16 + l15;
                FragU t;
                t.u = *reinterpret_cast<const uint4*>(sh_d + row * 68 + kk * 16 + 4 * l4);
                af[mt] = t.v;
            }
            #pragma unroll
            for (int mt = 0; mt < 2; ++mt)
                #pragma unroll
                for (int nt = 0; nt < 4; ++nt)
                    acc[mt][nt] = __builtin_amdgcn_mfma_f32_16x16x32_bf16(
                        af[mt], bfrag[nt][kk], acc[mt][nt], 0, 0, 0);
        }

        if (STATS) {
            #pragma unroll
            for (int nt = 0; nt < 4; ++nt) {
                float t1 = 0.f, t2 = 0.f;
                #pragma unroll
                for (int mt = 0; mt < 2; ++mt)
                    #pragma unroll
                    for (int r = 0; r < 4; ++r) {
                        float v = acc[mt][nt][r];
                        t1 += v;
                        t2 += v * v;
                    }
                s1[nt] += t1;
                s2[nt] += t2;
            }
        } else {
            // y_e = sum_c relu(h*A + B) * W2[c]  (+ b2)
            float pw[2][4];
            #pragma unroll
            for (int mt = 0; mt < 2; ++mt)
                #pragma unroll
                for (int r = 0; r < 4; ++r) {
                    float acc_y = 0.f;
                    #pragma unroll
                    for (int nt = 0; nt < 4; ++nt) {
                        float z = acc[mt][nt][r] * a_n[nt] + b_n[nt];
                        z = fmaxf(z, 0.f);
                        acc_y += z * w2_n[nt];
                    }
                    pw[mt][r] = acc_y;
                }
            #pragma unroll
            for (int off = 1; off < 16; off <<= 1)
                #pragma unroll
                for (int mt = 0; mt < 2; ++mt)
                    #pragma unroll
                    for (int r = 0; r < 4; ++r)
                        pw[mt][r] += __shfl_xor(pw[mt][r], off, 64);
            if (l15 == 0) {
                #pragma unroll
                for (int mt = 0; mt < 2; ++mt)
                    #pragma unroll
                    for (int r = 0; r < 4; ++r) {
                        const int el = wm * 32 + mt * 16 + l4 * 4 + r;
                        s_red[wn * 64 + el] = pw[mt][r];
                    }
            }
            __syncthreads();
            if (tid < 64) {
                float yv = s_red[tid] + s_red[64 + tid] + s_red[128 + tid]
                         + s_red[192 + tid] + b2v;
                y[tile * 64 + tid] = yv;
            }
        }
    }

    if (STATS) {
        #pragma unroll
        for (int nt = 0; nt < 4; ++nt) {
            s1[nt] += __shfl_xor(s1[nt], 16, 64);
            s1[nt] += __shfl_xor(s1[nt], 32, 64);
            s2[nt] += __shfl_xor(s2[nt], 16, 64);
            s2[nt] += __shfl_xor(s2[nt], 32, 64);
        }
        __syncthreads();
        s_red[tid] = 0.f;
        __syncthreads();
        if (l4 == 0) {
            #pragma unroll
            for (int nt = 0; nt < 4; ++nt) {
                const int c = wn * 64 + nt * 16 + l15;
                atomicAdd(&s_red[c],       s1[nt]);
                atomicAdd(&s_red[256 + c], s2[nt]);
            }
        }
        __syncthreads();
        atomicAdd(&gstat[tid], s_red[tid]);
    }
}

extern "C" void kernel_launch(void* const* d_in, const int* in_sizes, int n_in,
                              void* d_out, int out_size, void* d_ws, size_t ws_size,
                              hipStream_t stream) {
    const float* nodes = (const float*)d_in[0];
    const int*   eidx  = (const int*)d_in[1];
    const float* W1    = (const float*)d_in[2];
    // d_in[3] = b1 : analytically cancelled by batch-norm, unused
    const float* gamma = (const float*)d_in[4];
    const float* beta  = (const float*)d_in[5];
    const float* W2    = (const float*)d_in[6];
    const float* b2    = (const float*)d_in[7];

    float* ws    = (float*)d_ws;
    float* gstat = ws;          // 512 f32: sum_h[256], sumsq_h[256]
    float* nAB   = ws + 512;    // 512 f32: A[256], B[256]
    float* y     = (float*)d_out;

    zero_stats_kernel<<<1, 512, 0, stream>>>(gstat);
    hadamard_mlp_kernel<true><<<MAIN_GRID, 512, 0, stream>>>(
        nodes, eidx, W1, W2, b2, gstat, nAB, y);
    finalize_stats_kernel<<<1, 256, 0, stream>>>(gstat, gamma, beta, nAB);
    hadamard_mlp_kernel<false><<<MAIN_GRID, 512, 0, stream>>>(
        nodes, eidx, W1, W2, b2, gstat, nAB, y);
}